// Round 5
// baseline (1247.734 us; speedup 1.0000x reference)
//
#include <hip/hip_runtime.h>
#include <stdint.h>
#include <stddef.h>

// NCA fused kernel for MI355X (gfx950).
//   p[b,y,x,o] = sum_{i,dy,dx} h[b,y+dy,x+dx,i] * conv_w[o,i,dx+1,dy+1]
// conv+fc_first fused into one GEMM via W1c[n][k=(tap,i)].
//
// R5: interim/first layers moved to 32x32x16 MFMA (32768 FLOP / ~8 cyc vs
// 16384 / ~4.85 -> ~17% lower MFMA floor, 4x fewer MFMA instrs, 2x fewer
// ds_read_b128); T5 setprio around MFMA clusters. Structure from R4 kept:
// 128 cells/block as 2 tiles, shared weight-fragment stream (pre-shuffled
// to lane-linear), in-place LDS update, vectorized phase A.
// R2 lesson: keep live regs <= ~120 under (512,4)'s 128 budget. acc=64.

typedef __bf16 bf16_t;
typedef bf16_t bf16x8 __attribute__((ext_vector_type(8)));
typedef bf16_t bf16x4 __attribute__((ext_vector_type(4)));
typedef float  f32x4  __attribute__((ext_vector_type(4)));
typedef float  f32x16 __attribute__((ext_vector_type(16)));

#define N_B     8
#define N_H     128
#define N_W     128
#define N_C     16
#define HID     256
#define N_L     3
#define N_STEPS 16
#define M_TILE  128
#define THREADS 512
#define N_CELLS (N_B * N_H * N_W)
#define K1      160   // conv+fc1 fused K: 144 padded to 160
#define KK1     10    // K1/16  (32x32x16 K-steps, layer 1)
#define KKH     16    // HID/16 (32x32x16 K-steps, interim layers)
#define KKL     8     // HID/32 (16x16x32 K-steps, last layer)

// XOR swizzle: breaks 512B-row-stride same-bank conflicts on LDS access
// (apply identically on write and read; bijective within each 128B group)
__device__ __forceinline__ int swz(int row, int byteoff) {
  return byteoff ^ ((row & 7) << 4);
}

// Weights pre-shuffled to 32x32x16 A-fragment order (lane-linear b128):
//   elem idx = (((wid*KK + kk)*64 + lane)*8 + e
//   holds W[col][k], col = wid*32 + (lane&31), k = kk*16 + (lane>>5)*8 + e.
// Last layer stays 16x16x32 order: idx=(kk*64+lane)*8+e,
//   col = lane&15, k = kk*32 + (lane>>4)*8 + e.
__global__ void prep_kernel(const float* __restrict__ conv_w,
                            const float* __restrict__ w_first,
                            const float* __restrict__ w_interim,
                            const float* __restrict__ w_last,
                            bf16_t* __restrict__ W1c_lin,
                            bf16_t* __restrict__ Wi_lin,
                            bf16_t* __restrict__ Wl_lin) {
  const int tid = blockIdx.x * blockDim.x + threadIdx.x;
  const int nth = gridDim.x * blockDim.x;
  // fused conv+fc1 weights, K1=160 (k>=144 zero pad), KK1=10
  for (int idx = tid; idx < 256 * K1; idx += nth) {
    int e = idx & 7, lane = (idx >> 3) & 63, r = idx >> 9;
    int kk = r % KK1, wid = r / KK1;
    int col = wid * 32 + (lane & 31);
    int k = kk * 16 + (lane >> 5) * 8 + e;
    float v = 0.f;
    if (k < 144) {
      int tap = k >> 4, i = k & 15;
      int dy = tap / 3 - 1, dx = tap % 3 - 1;
      for (int o = 0; o < 16; ++o)
        v += w_first[col * 16 + o] * conv_w[((o * 16 + i) * 3 + (dx + 1)) * 3 + (dy + 1)];
    }
    W1c_lin[idx] = (bf16_t)v;
  }
  for (int idx = tid; idx < N_L * HID * HID; idx += nth) {
    int l = idx >> 16, idx2 = idx & 65535;
    int e = idx2 & 7, lane = (idx2 >> 3) & 63, r = idx2 >> 9;
    int kk = r & 15, wid = r >> 4;
    int col = wid * 32 + (lane & 31);
    int k = kk * 16 + (lane >> 5) * 8 + e;
    Wi_lin[idx] = (bf16_t)w_interim[(l * HID + col) * HID + k];
  }
  for (int idx = tid; idx < N_C * HID; idx += nth) {
    int e = idx & 7, lane = (idx >> 3) & 63, kk = idx >> 9;
    int col = lane & 15;
    int k = kk * 32 + (lane >> 4) * 8 + e;
    Wl_lin[idx] = (bf16_t)w_last[col * HID + k];
  }
}

// One MLP layer applied IN-PLACE to BOTH 64-row tiles (32x32x16 MFMA):
//   buf* <- relu(buf* @ W^T + bias), N=256; 8 waves, each owns a 32-wide
// N-slice. Swapped MFMA: D = mfma(Wfrag, actfrag); D col = cell (lane&31),
// D row = n = nbase + (reg&3) + 8*(reg>>2) + 4*(lane>>5)  [verified m74/m101]
// -> reg-quads are 4 consecutive channels -> packed b64 LDS writes.
// One weight-fragment load feeds 4 MFMAs (2 tiles x 2 m-frags).
// Contains an internal __syncthreads between consume and in-place write.
template <int KK>
__device__ __forceinline__ void mlp2(uint8_t* __restrict__ b0,
                                     uint8_t* __restrict__ b1,
                                     const bf16_t* __restrict__ Wlin,
                                     const float* __restrict__ bias,
                                     int lane, int wid) {
  const int lc = lane & 31;   // cell-within-32 (B/D col) and weight col
  const int lh = lane >> 5;   // k-half; also n-offset 4*lh in D
  const int nbase = wid * 32;
  const bf16x8* __restrict__ wfrag = (const bf16x8*)Wlin + (wid * KK) * 64 + lane;
  f32x16 acc[2][2];           // [tile][m-frag], 64 VGPR total
#pragma unroll
  for (int q = 0; q < 4; ++q) {
    f32x4 bq = *(const f32x4*)(bias + nbase + 8 * q + 4 * lh);
#pragma unroll
    for (int t = 0; t < 2; ++t)
#pragma unroll
      for (int m = 0; m < 2; ++m)
#pragma unroll
        for (int j = 0; j < 4; ++j) acc[t][m][4 * q + j] = bq[j];
  }
#pragma unroll
  for (int kk = 0; kk < KK; ++kk) {
    bf16x8 w = wfrag[kk * 64];
    const int kb = kk * 32 + lh * 16;   // byte offset of this lane's 8 bf16
    bf16x8 a00 = *(const bf16x8*)(b0 + lc * 512 + swz(lc, kb));
    bf16x8 a01 = *(const bf16x8*)(b0 + (32 + lc) * 512 + swz(32 + lc, kb));
    bf16x8 a10 = *(const bf16x8*)(b1 + lc * 512 + swz(lc, kb));
    bf16x8 a11 = *(const bf16x8*)(b1 + (32 + lc) * 512 + swz(32 + lc, kb));
    __builtin_amdgcn_s_setprio(1);
    acc[0][0] = __builtin_amdgcn_mfma_f32_32x32x16_bf16(w, a00, acc[0][0], 0, 0, 0);
    acc[0][1] = __builtin_amdgcn_mfma_f32_32x32x16_bf16(w, a01, acc[0][1], 0, 0, 0);
    acc[1][0] = __builtin_amdgcn_mfma_f32_32x32x16_bf16(w, a10, acc[1][0], 0, 0, 0);
    acc[1][1] = __builtin_amdgcn_mfma_f32_32x32x16_bf16(w, a11, acc[1][1], 0, 0, 0);
    __builtin_amdgcn_s_setprio(0);
  }
  __syncthreads();  // both tiles fully consumed by ALL waves; safe to overwrite
#pragma unroll
  for (int t = 0; t < 2; ++t) {
    uint8_t* tb = t ? b1 : b0;
#pragma unroll
    for (int m = 0; m < 2; ++m) {
      int row = m * 32 + lc;            // cell
#pragma unroll
      for (int q = 0; q < 4; ++q) {
        bf16x4 wv;
#pragma unroll
        for (int j = 0; j < 4; ++j) wv[j] = (bf16_t)fmaxf(acc[t][m][4 * q + j], 0.f);
        int nb = (nbase + 8 * q + 4 * lh) * 2;  // byte offset of 4 channels
        *(bf16x4*)(tb + row * 512 + swz(row, nb)) = wv;
      }
    }
  }
}

__global__ __launch_bounds__(THREADS, 4)
void nca_step_kernel(const float* __restrict__ hsrc, float* __restrict__ hdst,
                     const bf16_t* __restrict__ W1c_lin, const bf16_t* __restrict__ Wi_lin,
                     const bf16_t* __restrict__ Wl_lin,
                     const float* __restrict__ b_first,
                     const float* __restrict__ b_interim) {
  __shared__ __align__(16) uint8_t buf[2][64 * 512];   // 64 KB, 2 tiles

  const int t = threadIdx.x;
  const int lane = t & 63;
  const int wid = t >> 6;
  const int by = blockIdx.x;      // block = one image row: 1024 = 8 b x 128 y
  const int b = by >> 7;
  const int y = by & 127;

  // ---- Phase A: patch[128][160] as 2 tiles of [64][512B] (k = tap*16 + i)
  // thread t: cell m = t&127 (x coordinate), k4-chunk group q = t>>7 (0..3)
  {
    const int m = t & 127;
    const int q = t >> 7;
    uint8_t* tb = buf[m >> 6];
    const int row = m & 63;
#pragma unroll
    for (int jj = 0; jj < 9; ++jj) {
      int k4 = q * 9 + jj;             // 0..35 real chunks (k = 4*k4)
      int tap = k4 >> 2, i0 = (k4 & 3) * 4;
      int dy = tap / 3 - 1, dx = tap % 3 - 1;
      int yy = y + dy, xx = m + dx;
      f32x4 v = {0.f, 0.f, 0.f, 0.f};
      if ((unsigned)yy < (unsigned)N_H && (unsigned)xx < (unsigned)N_W)
        v = *(const f32x4*)(hsrc + ((b * N_H + yy) * N_W + xx) * N_C + i0);
      bf16x4 w;
#pragma unroll
      for (int j = 0; j < 4; ++j) w[j] = (bf16_t)v[j];
      *(bf16x4*)(tb + row * 512 + swz(row, 8 * k4)) = w;
    }
    // zero pad k4 = 36..39 (k = 144..159)
    bf16x4 z;
#pragma unroll
    for (int j = 0; j < 4; ++j) z[j] = (bf16_t)0.f;
    int k4p = 36 + q;
    *(bf16x4*)(tb + row * 512 + swz(row, 8 * k4p)) = z;
  }
  __syncthreads();

  mlp2<KK1>(buf[0], buf[1], W1c_lin, b_first, lane, wid);   // conv+fc1
  __syncthreads();
  mlp2<KKH>(buf[0], buf[1], Wi_lin + 0 * HID * HID, b_interim + 0 * HID, lane, wid);
  __syncthreads();
  mlp2<KKH>(buf[0], buf[1], Wi_lin + 1 * HID * HID, b_interim + 1 * HID, lane, wid);
  __syncthreads();
  mlp2<KKH>(buf[0], buf[1], Wi_lin + 2 * HID * HID, b_interim + 2 * HID, lane, wid);
  __syncthreads();

  // ---- Last layer: out[128][16] = act @ w_last^T ; residual in f32.
  // 16x16x32 swapped; wave w handles cells w*16..w*16+15 (tile = w>>2,
  // rows (w&3)*16+lr); lane holds cell, channels 4*lk.. -> float4 global I/O.
  {
    const int lr = lane & 15;
    const int lk = lane >> 4;
    const uint8_t* tb = buf[wid >> 2];
    const int rb = (wid & 3) * 16;
    const bf16x8* __restrict__ wl = (const bf16x8*)Wl_lin + lane;
    f32x4 acc = {0.f, 0.f, 0.f, 0.f};
#pragma unroll
    for (int kk = 0; kk < KKL; ++kk) {
      int row = rb + lr;
      bf16x8 a = *(const bf16x8*)(tb + row * 512 + swz(row, kk * 64 + lk * 16));
      bf16x8 bb = wl[kk * 64];
      acc = __builtin_amdgcn_mfma_f32_16x16x32_bf16(bb, a, acc, 0, 0, 0);
    }
    const int cell = by * M_TILE + wid * 16 + lr;
    const int gi = cell * N_C + lk * 4;
    f32x4 r = *(const f32x4*)(hsrc + gi);
#pragma unroll
    for (int j = 0; j < 4; ++j) r[j] += acc[j];
    *(f32x4*)(hdst + gi) = r;
  }
}

extern "C" void kernel_launch(void* const* d_in, const int* in_sizes, int n_in,
                              void* d_out, int out_size, void* d_ws, size_t ws_size,
                              hipStream_t stream) {
  const float* x         = (const float*)d_in[0];
  const float* conv_w    = (const float*)d_in[1];
  const float* w_first   = (const float*)d_in[2];
  const float* b_first   = (const float*)d_in[3];
  const float* w_interim = (const float*)d_in[4];
  const float* b_interim = (const float*)d_in[5];
  const float* w_last    = (const float*)d_in[6];
  // d_in[7] = steps (scalar, == 16 per reference; fixed at compile time)

  float* xfinal = (float*)d_out;
  float* hist   = xfinal + (size_t)N_CELLS * N_C;  // 17 slots of h-state

  bf16_t* W1c_lin = (bf16_t*)d_ws;            // 256*160
  bf16_t* Wi_lin  = W1c_lin + 256 * K1;       // 3*256*256
  bf16_t* Wl_lin  = Wi_lin + N_L * HID * HID; // 16*256   (~483 KB total)

  prep_kernel<<<64, 256, 0, stream>>>(conv_w, w_first, w_interim, w_last,
                                      W1c_lin, Wi_lin, Wl_lin);
  hipMemcpyAsync(hist, x, (size_t)N_CELLS * N_C * sizeof(float),
                 hipMemcpyDeviceToDevice, stream);
  for (int s = 0; s < N_STEPS; ++s)
    nca_step_kernel<<<N_CELLS / M_TILE, THREADS, 0, stream>>>(
        hist + (size_t)s * N_CELLS * N_C, hist + (size_t)(s + 1) * N_CELLS * N_C,
        W1c_lin, Wi_lin, Wl_lin, b_first, b_interim);
  hipMemcpyAsync(xfinal, hist + (size_t)N_STEPS * N_CELLS * N_C,
                 (size_t)N_CELLS * N_C * sizeof(float),
                 hipMemcpyDeviceToDevice, stream);
}